// Round 2
// baseline (421.281 us; speedup 1.0000x reference)
//
#include <hip/hip_runtime.h>
#include <hip/hip_bf16.h>

typedef float f32x4 __attribute__((ext_vector_type(4)));
typedef short s16x8 __attribute__((ext_vector_type(8)));

#define MFMA16(a, b, c) __builtin_amdgcn_mfma_f32_16x16x32_bf16(a, b, c, 0, 0, 0)

static constexpr int B_ = 2, S_ = 2048, D_ = 1024, H_ = 16, HD_ = 64;
static constexpr float ATT_SCALE = 0.125f;  // HD^-0.5

__device__ __forceinline__ float bf2f(unsigned short u) {
    unsigned int x = ((unsigned int)u) << 16;
    return __builtin_bit_cast(float, x);
}
__device__ __forceinline__ unsigned short f2bf(float f) {
    unsigned int u = __builtin_bit_cast(unsigned int, f);
    u += 0x7fffu + ((u >> 16) & 1);  // round-to-nearest-even
    return (unsigned short)(u >> 16);
}

// ---------------------------------------------------------------------------
// Transpose + convert: Wt_bf16[(h*64+e)*1024 + d] = W_f32[h*65536 + d*64 + e]
// ---------------------------------------------------------------------------
__global__ __launch_bounds__(256) void transpose_w(const float* __restrict__ W,
                                                   unsigned short* __restrict__ Wt) {
    int idx = blockIdx.x * 256 + threadIdx.x;
    int e = idx & 63, d = (idx >> 6) & 1023, h = idx >> 16;
    Wt[(h * 64 + e) * 1024 + d] = f2bf(W[idx]);
}

// ---------------------------------------------------------------------------
// C[M=4096][N=1024] = A[4096][1024] * Bt[1024][1024]^T + bias
// A row-major (fp32 or bf16), Bt row-major B^T (fp32 or bf16); MFMA in bf16.
// C32ROW true : C row-major fp32 [M][N]
// C32ROW false: C scatter bf16 to [B,H,S,HD] (m = b*2048+s, n = h*64+e)
// 64x64 tile, BK=32, 4 waves, each wave a 32x32 quadrant (2x2 MFMA tiles).
// ---------------------------------------------------------------------------
template <bool A32, bool B32, bool C32ROW>
__global__ __launch_bounds__(256) void gemm_bt(const void* __restrict__ Ap,
                                               const void* __restrict__ Bp,
                                               const float* __restrict__ bias,
                                               void* __restrict__ Cp) {
    constexpr int Kd = 1024, Nd = 1024;
    constexpr int LDT = 40;  // 32 + 8 pad: breaks stride-64B LDS bank conflict
    __shared__ unsigned short As[64 * LDT];
    __shared__ unsigned short Bs[64 * LDT];
    const int tid = threadIdx.x;
    const int lane = tid & 63;
    const int w = tid >> 6;
    const int wm = w & 1, wn = w >> 1;
    const int l16 = lane & 15, quad = lane >> 4;
    const int m0 = blockIdx.y * 64, n0 = blockIdx.x * 64;
    const int lrow = tid >> 2, lcol = (tid & 3) * 8;

    f32x4 acc[2][2] = {};
    for (int k0 = 0; k0 < Kd; k0 += 32) {
        s16x8 av, bv;
        if (A32) {
            const float* A = (const float*)Ap;
            f32x4 a0 = *(const f32x4*)&A[(size_t)(m0 + lrow) * Kd + k0 + lcol];
            f32x4 a1 = *(const f32x4*)&A[(size_t)(m0 + lrow) * Kd + k0 + lcol + 4];
            for (int j = 0; j < 4; j++) { av[j] = (short)f2bf(a0[j]); av[4 + j] = (short)f2bf(a1[j]); }
        } else {
            const unsigned short* A = (const unsigned short*)Ap;
            av = *(const s16x8*)&A[(size_t)(m0 + lrow) * Kd + k0 + lcol];
        }
        if (B32) {
            const float* Bt = (const float*)Bp;
            f32x4 b0 = *(const f32x4*)&Bt[(size_t)(n0 + lrow) * Kd + k0 + lcol];
            f32x4 b1 = *(const f32x4*)&Bt[(size_t)(n0 + lrow) * Kd + k0 + lcol + 4];
            for (int j = 0; j < 4; j++) { bv[j] = (short)f2bf(b0[j]); bv[4 + j] = (short)f2bf(b1[j]); }
        } else {
            const unsigned short* Bt = (const unsigned short*)Bp;
            bv = *(const s16x8*)&Bt[(size_t)(n0 + lrow) * Kd + k0 + lcol];
        }
        __syncthreads();  // previous iteration's frag reads done
        *(s16x8*)&As[lrow * LDT + lcol] = av;
        *(s16x8*)&Bs[lrow * LDT + lcol] = bv;
        __syncthreads();
        s16x8 af[2], bfr[2];
        af[0]  = *(const s16x8*)&As[(wm * 32 + l16) * LDT + quad * 8];
        af[1]  = *(const s16x8*)&As[(wm * 32 + 16 + l16) * LDT + quad * 8];
        bfr[0] = *(const s16x8*)&Bs[(wn * 32 + l16) * LDT + quad * 8];
        bfr[1] = *(const s16x8*)&Bs[(wn * 32 + 16 + l16) * LDT + quad * 8];
        acc[0][0] = MFMA16(af[0], bfr[0], acc[0][0]);
        acc[0][1] = MFMA16(af[0], bfr[1], acc[0][1]);
        acc[1][0] = MFMA16(af[1], bfr[0], acc[1][0]);
        acc[1][1] = MFMA16(af[1], bfr[1], acc[1][1]);
    }
    // C/D layout: row = quad*4 + r, col = lane&15  (m89-verified)
    for (int i = 0; i < 2; i++)
        for (int j = 0; j < 2; j++)
            for (int r = 0; r < 4; r++) {
                int mg = m0 + wm * 32 + i * 16 + quad * 4 + r;
                int ng = n0 + wn * 32 + j * 16 + l16;
                float v = acc[i][j][r] + bias[ng];
                if (C32ROW) {
                    ((float*)Cp)[(size_t)mg * Nd + ng] = v;
                } else {
                    int b = mg >> 11, s = mg & 2047, h = ng >> 6, e = ng & 63;
                    ((unsigned short*)Cp)[(((size_t)(b * H_ + h) * S_) + s) * HD_ + e] = f2bf(v);
                }
            }
}

// ---------------------------------------------------------------------------
// Flash attention: one wave per 16 Q rows of one (b,h). 32-key steps.
// Q/K/V are [B,H,S,HD] bf16 (ours). Output -> concat[B,S,H*HD] bf16 (ours).
// ---------------------------------------------------------------------------
__global__ __launch_bounds__(64) void flash_attn(const unsigned short* __restrict__ Qb,
                                                 const unsigned short* __restrict__ Kb,
                                                 const unsigned short* __restrict__ Vb,
                                                 unsigned short* __restrict__ Cc) {
    __shared__ unsigned short P[16 * 32];
    const int lane = threadIdx.x;
    const int l16 = lane & 15, quad = lane >> 4;
    const int bh = blockIdx.y;        // b*16 + h
    const int q0 = blockIdx.x * 16;
    const size_t base = (size_t)bh * S_ * HD_;

    // Q A-fragments: A[m=lane&15][k=quad*8+j]
    const unsigned short* Qp = Qb + base + (size_t)(q0 + l16) * HD_;
    s16x8 aq0 = *(const s16x8*)&Qp[quad * 8];
    s16x8 aq1 = *(const s16x8*)&Qp[32 + quad * 8];

    float m_run[4], l_run[4];
    f32x4 o[4] = {};
    for (int r = 0; r < 4; r++) { m_run[r] = -1e30f; l_run[r] = 0.f; }

    for (int k0 = 0; k0 < S_; k0 += 32) {
        // K B-fragments: B[k=d][n=key] = K[key][d]; contiguous 16B in d.
        const unsigned short* Kp0 = Kb + base + (size_t)(k0 + l16) * HD_;
        const unsigned short* Kp1 = Kp0 + 16 * HD_;
        s16x8 b00 = *(const s16x8*)&Kp0[quad * 8];
        s16x8 b01 = *(const s16x8*)&Kp0[32 + quad * 8];
        s16x8 b10 = *(const s16x8*)&Kp1[quad * 8];
        s16x8 b11 = *(const s16x8*)&Kp1[32 + quad * 8];
        f32x4 s0 = {}, s1 = {};
        s0 = MFMA16(aq0, b00, s0);
        s0 = MFMA16(aq1, b01, s0);
        s1 = MFMA16(aq0, b10, s1);
        s1 = MFMA16(aq1, b11, s1);

        float alpha[4];
        for (int r = 0; r < 4; r++) {
            float x0 = s0[r] * ATT_SCALE, x1 = s1[r] * ATT_SCALE;
            float v = fmaxf(x0, x1);
            v = fmaxf(v, __shfl_xor(v, 1));
            v = fmaxf(v, __shfl_xor(v, 2));
            v = fmaxf(v, __shfl_xor(v, 4));
            v = fmaxf(v, __shfl_xor(v, 8));
            float mnew = fmaxf(m_run[r], v);
            alpha[r] = __expf(m_run[r] - mnew);
            m_run[r] = mnew;
            float p0 = __expf(x0 - mnew), p1 = __expf(x1 - mnew);
            float rs = p0 + p1;
            rs += __shfl_xor(rs, 1);
            rs += __shfl_xor(rs, 2);
            rs += __shfl_xor(rs, 4);
            rs += __shfl_xor(rs, 8);
            l_run[r] = l_run[r] * alpha[r] + rs;
            // P in C-layout -> LDS [16 rows][32 keys]
            P[(quad * 4 + r) * 32 + l16] = f2bf(p0);
            P[(quad * 4 + r) * 32 + 16 + l16] = f2bf(p1);
        }
        for (int t = 0; t < 4; t++) {
            o[t][0] *= alpha[0]; o[t][1] *= alpha[1];
            o[t][2] *= alpha[2]; o[t][3] *= alpha[3];
        }
        __syncthreads();
        // P back out in A-layout
        s16x8 pA = *(const s16x8*)&P[l16 * 32 + quad * 8];
        __syncthreads();
        // PV: B[k=key][n=e]; scalar loads (stride HD*2B) — optimize next round
        const unsigned short* Vp = Vb + base + (size_t)k0 * HD_;
        for (int t = 0; t < 4; t++) {
            s16x8 bv;
#pragma unroll
            for (int j = 0; j < 8; j++)
                bv[j] = (short)Vp[(quad * 8 + j) * HD_ + t * 16 + l16];
            o[t] = MFMA16(pA, bv, o[t]);
        }
    }
    const int b = bh >> 4, h = bh & 15;
    for (int t = 0; t < 4; t++)
        for (int r = 0; r < 4; r++) {
            int srow = q0 + quad * 4 + r;
            float v = o[t][r] / l_run[r];
            Cc[((size_t)(b * S_ + srow)) * D_ + h * HD_ + t * 16 + l16] = f2bf(v);
        }
}

// ---------------------------------------------------------------------------
extern "C" void kernel_launch(void* const* d_in, const int* in_sizes, int n_in,
                              void* d_out, int out_size, void* d_ws, size_t ws_size,
                              hipStream_t stream) {
    const float* K_in = (const float*)d_in[0];
    const float* V_in = (const float*)d_in[1];
    const float* Q_in = (const float*)d_in[2];
    const float* Wk   = (const float*)d_in[3];
    const float* bk   = (const float*)d_in[4];
    const float* Wq   = (const float*)d_in[5];
    const float* bq   = (const float*)d_in[6];
    const float* Wv   = (const float*)d_in[7];
    const float* bv   = (const float*)d_in[8];
    const float* Wp   = (const float*)d_in[9];
    const float* bp   = (const float*)d_in[10];

    unsigned short* ws = (unsigned short*)d_ws;
    const size_t WSZ = 1024 * 1024;                 // one transposed weight (elements)
    const size_t TSZ = (size_t)B_ * H_ * S_ * HD_;  // 4,194,304 elements
    unsigned short* Qb  = ws;                        // bf16 [B,H,S,HD]
    unsigned short* Kb  = Qb + TSZ;
    unsigned short* Vb  = Kb + TSZ;
    unsigned short* Wtq = Vb + TSZ;                  // bf16 [1024][1024]
    unsigned short* Wtk = Wtq + WSZ;
    unsigned short* Wtv = Wtk + WSZ;
    unsigned short* Cc  = Wtq;  // alias: Wt* are dead once flash runs (same stream)
    // total ws: 3*TSZ + max(3*WSZ, TSZ) = 16.78M ushorts ≈ 33.6 MB

    transpose_w<<<4096, 256, 0, stream>>>(Wq, Wtq);
    transpose_w<<<4096, 256, 0, stream>>>(Wk, Wtk);
    transpose_w<<<4096, 256, 0, stream>>>(Wv, Wtv);

    dim3 g(16, 64);  // N/64, M/64
    gemm_bt<true, false, false><<<g, 256, 0, stream>>>(Q_in, Wtq, bq, Qb);
    gemm_bt<true, false, false><<<g, 256, 0, stream>>>(K_in, Wtk, bk, Kb);
    gemm_bt<true, false, false><<<g, 256, 0, stream>>>(V_in, Wtv, bv, Vb);

    flash_attn<<<dim3(128, 32), 64, 0, stream>>>(Qb, Kb, Vb, Cc);

    gemm_bt<false, true, true><<<g, 256, 0, stream>>>(Cc, Wp, bp, d_out);
}